// Round 10
// baseline (480.670 us; speedup 1.0000x reference)
//
#include <hip/hip_runtime.h>
#include <math.h>

#define NS 10000
#define LSEQ 32
#define DDIM 300
#define HDIM 300
#define BB 256
#define NMAX 128
#define MMAX 128
#define EPSR 0.1f
#define SITERS 50
#define KPAD 320
#define NPADW 384

typedef __attribute__((ext_vector_type(8))) short bf16x8;
typedef __attribute__((ext_vector_type(4))) float f32x4;

__device__ __forceinline__ ushort f2bf(float x) {
  union { float f; unsigned u; } c; c.f = x;
  unsigned r = (c.u + 0x7fffu + ((c.u >> 16) & 1u)) >> 16;
  return (ushort)r;
}
__device__ __forceinline__ float bf2f(ushort h) {
  union { unsigned u; float f; } c; c.u = ((unsigned)h) << 16;
  return c.f;
}

// ------- K1: embedding + masked mean pool -> enc hi/lo [NS][KPAD] bf16 -----
__global__ __launch_bounds__(256) void k_embed(const int* __restrict__ data,
                                               const float* __restrict__ emb,
                                               ushort* __restrict__ enchi,
                                               ushort* __restrict__ enclo) {
  __shared__ int ids[LSEQ];
  __shared__ __align__(16) float4 part[3][76];
  int s = blockIdx.x;
  int tid = threadIdx.x;
  if (tid < LSEQ) ids[tid] = data[s * LSEQ + tid];
  __syncthreads();
  int cnt = 0;
#pragma unroll
  for (int t = 0; t < LSEQ; ++t) cnt += (ids[t] != 0) ? 1 : 0;
  int g = tid / 75, d = tid - g * 75;
  const float4* emb4 = (const float4*)emb;
  if (g < 3) {
    float4 acc = make_float4(0.f, 0.f, 0.f, 0.f);
    for (int t = g; t < LSEQ; t += 3) {
      int id = ids[t];
      if (id != 0) {
        float4 e = emb4[(size_t)id * 75 + d];
        acc.x += e.x; acc.y += e.y; acc.z += e.z; acc.w += e.w;
      }
    }
    part[g][d] = acc;
  }
  __syncthreads();
  if (g == 0) {
    float4 a = part[0][d], b = part[1][d], c = part[2][d];
    float inv = 1.f / (float)(cnt > 0 ? cnt : 1);
    float v[4] = {(a.x + b.x + c.x) * inv, (a.y + b.y + c.y) * inv,
                  (a.z + b.z + c.z) * inv, (a.w + b.w + c.w) * inv};
    ushort4 h, l;
    h.x = f2bf(v[0]); l.x = f2bf(v[0] - bf2f(h.x));
    h.y = f2bf(v[1]); l.y = f2bf(v[1] - bf2f(h.y));
    h.z = f2bf(v[2]); l.z = f2bf(v[2] - bf2f(h.z));
    h.w = f2bf(v[3]); l.w = f2bf(v[3] - bf2f(h.w));
    *(ushort4*)&enchi[(size_t)s * KPAD + d * 4] = h;
    *(ushort4*)&enclo[(size_t)s * KPAD + d * 4] = l;
  } else if (g == 1 && d < 5) {
    ushort4 z; z.x = z.y = z.z = z.w = 0;
    *(ushort4*)&enchi[(size_t)s * KPAD + 300 + d * 4] = z;
    *(ushort4*)&enclo[(size_t)s * KPAD + 300 + d * 4] = z;
  }
}

// ------- K2: all weight converts in one dispatch ---------------------------
// W1,W2 -> transposed hi/lo [NPADW][KPAD]; Wc -> concat-transposed [640][KPAD]
__global__ __launch_bounds__(256) void k_cvt_all(
    const float* __restrict__ W1, const float* __restrict__ W2,
    const float* __restrict__ Wc, ushort* __restrict__ W1hi,
    ushort* __restrict__ W1lo, ushort* __restrict__ W2hi,
    ushort* __restrict__ W2lo, ushort* __restrict__ Wchi,
    ushort* __restrict__ Wclo) {
  int i = blockIdx.x * 256 + threadIdx.x;
  const int SA = NPADW * KPAD;
  const int SC = 640 * KPAD;
  float v = 0.f;
  ushort *ph, *pl;
  int idx;
  if (i < SA) {
    idx = i;
    int n = idx / KPAD, k = idx - n * KPAD;
    if (n < HDIM && k < DDIM) v = W1[(size_t)k * HDIM + n];
    ph = W1hi; pl = W1lo;
  } else if (i < 2 * SA) {
    idx = i - SA;
    int n = idx / KPAD, k = idx - n * KPAD;
    if (n < HDIM && k < HDIM) v = W2[(size_t)k * HDIM + n];
    ph = W2hi; pl = W2lo;
  } else if (i < 2 * SA + SC) {
    idx = i - 2 * SA;
    int n = idx / KPAD, k = idx - n * KPAD;
    if (k < HDIM && n < 2 * HDIM)
      v = (n < HDIM) ? Wc[(size_t)k * HDIM + n]
                     : Wc[(size_t)(HDIM + k) * HDIM + (n - HDIM)];
    ph = Wchi; pl = Wclo;
  } else {
    return;
  }
  ushort h = f2bf(v);
  ph[idx] = h;
  pl[idx] = f2bf(v - bf2f(h));
}

// ------- K3: MFMA GEMM, hi/lo 3-term, 64x128 tile, wave = 32x64 ------------
// A hi/lo [M][KPAD]; B hi/lo transposed [>=n0+128][KPAD]. Grid y covers N in
// 128-col pairs (A-traffic reduced vs 64-col tiles). Numerically identical
// accumulation order to the 64x64 version (chunk-ascending, 3-term).
__global__ __launch_bounds__(256) void k_gemm_mfma(
    const ushort* __restrict__ Ahi, const ushort* __restrict__ Alo,
    const ushort* __restrict__ BhiT, const ushort* __restrict__ BloT,
    const float* __restrict__ bias, int M, int N, int relu,
    float* __restrict__ Cf, ushort* __restrict__ Chi,
    ushort* __restrict__ Clo) {
  __shared__ __align__(16) ushort ldsA[2][64][40];
  __shared__ __align__(16) ushort ldsB[2][128][40];
  int tid = threadIdx.x;
  int m0 = blockIdx.x * 64, n0 = blockIdx.y * 128;
  int rowA = tid >> 2, chA = (tid & 3) * 8;
  int rowB = tid >> 1, chB = (tid & 1) * 16;
  bool mok = (m0 + rowA) < M;
  const ushort* pAh = Ahi + (size_t)(m0 + rowA) * KPAD + chA;
  const ushort* pAl = Alo + (size_t)(m0 + rowA) * KPAD + chA;
  const ushort* pBh = BhiT + (size_t)(n0 + rowB) * KPAD + chB;
  const ushort* pBl = BloT + (size_t)(n0 + rowB) * KPAD + chB;
  uint4 rAh, rAl, rBh0, rBh1, rBl0, rBl1;
  uint4 z4; z4.x = z4.y = z4.z = z4.w = 0;
  auto ld = [&](int c) {
    int o = c * 32;
    rAh = mok ? *(const uint4*)(pAh + o) : z4;
    rAl = mok ? *(const uint4*)(pAl + o) : z4;
    rBh0 = *(const uint4*)(pBh + o);
    rBh1 = *(const uint4*)(pBh + o + 8);
    rBl0 = *(const uint4*)(pBl + o);
    rBl1 = *(const uint4*)(pBl + o + 8);
  };
  auto st = [&]() {
    *(uint4*)&ldsA[0][rowA][chA] = rAh;
    *(uint4*)&ldsA[1][rowA][chA] = rAl;
    *(uint4*)&ldsB[0][rowB][chB] = rBh0;
    *(uint4*)&ldsB[0][rowB][chB + 8] = rBh1;
    *(uint4*)&ldsB[1][rowB][chB] = rBl0;
    *(uint4*)&ldsB[1][rowB][chB + 8] = rBl1;
  };
  int w = tid >> 6, lane = tid & 63;
  int q = lane >> 4, l16 = lane & 15;
  int mh = w >> 1, nh = w & 1;
  f32x4 zf = {0.f, 0.f, 0.f, 0.f};
  f32x4 acc[2][4];
#pragma unroll
  for (int s = 0; s < 2; ++s)
#pragma unroll
    for (int t = 0; t < 4; ++t) acc[s][t] = zf;
  ld(0); st(); __syncthreads();
  for (int c = 0; c < 10; ++c) {
    if (c < 9) ld(c + 1);
    bf16x8 ah0 = *(const bf16x8*)&ldsA[0][mh * 32 + l16][q * 8];
    bf16x8 ah1 = *(const bf16x8*)&ldsA[0][mh * 32 + 16 + l16][q * 8];
    bf16x8 al0 = *(const bf16x8*)&ldsA[1][mh * 32 + l16][q * 8];
    bf16x8 al1 = *(const bf16x8*)&ldsA[1][mh * 32 + 16 + l16][q * 8];
#pragma unroll
    for (int t = 0; t < 4; ++t) {
      int brow = nh * 64 + t * 16 + l16;
      bf16x8 bh = *(const bf16x8*)&ldsB[0][brow][q * 8];
      bf16x8 bl = *(const bf16x8*)&ldsB[1][brow][q * 8];
      acc[0][t] = __builtin_amdgcn_mfma_f32_16x16x32_bf16(ah0, bh, acc[0][t], 0, 0, 0);
      acc[0][t] = __builtin_amdgcn_mfma_f32_16x16x32_bf16(ah0, bl, acc[0][t], 0, 0, 0);
      acc[0][t] = __builtin_amdgcn_mfma_f32_16x16x32_bf16(al0, bh, acc[0][t], 0, 0, 0);
      acc[1][t] = __builtin_amdgcn_mfma_f32_16x16x32_bf16(ah1, bh, acc[1][t], 0, 0, 0);
      acc[1][t] = __builtin_amdgcn_mfma_f32_16x16x32_bf16(ah1, bl, acc[1][t], 0, 0, 0);
      acc[1][t] = __builtin_amdgcn_mfma_f32_16x16x32_bf16(al1, bh, acc[1][t], 0, 0, 0);
    }
    __syncthreads();
    if (c < 9) st();
    __syncthreads();
  }
#pragma unroll
  for (int t = 0; t < 4; ++t) {
    int n = n0 + nh * 64 + t * 16 + l16;
    bool nin = n < N;
    float bz = (bias && nin) ? bias[n] : 0.f;
#pragma unroll
    for (int s = 0; s < 2; ++s) {
#pragma unroll
      for (int r = 0; r < 4; ++r) {
        int m = m0 + mh * 32 + s * 16 + q * 4 + r;
        if (m >= M) continue;
        float v = acc[s][t][r] + bz;
        if (relu) v = v > 0.f ? v : 0.f;
        if (Cf && nin) Cf[(size_t)m * N + n] = v;
        if (Chi && n < KPAD) {
          ushort h = 0, l = 0;
          if (nin) { h = f2bf(v); l = f2bf(v - bf2f(h)); }
          Chi[(size_t)m * KPAD + n] = h;
          Clo[(size_t)m * KPAD + n] = l;
        }
      }
    }
  }
}

// --- K4: normalize henc (hi/lo) -> hn hi/lo [NS][KPAD] (unit rows) ---------
__global__ __launch_bounds__(256) void k_norm_split(
    const ushort* __restrict__ hehi, const ushort* __restrict__ helo,
    ushort* __restrict__ hnhi, ushort* __restrict__ hnlo) {
  int s = blockIdx.x * 4 + (threadIdx.x >> 6);
  int lane = threadIdx.x & 63;
  if (s >= NS) return;
  const ushort* ph = hehi + (size_t)s * KPAD;
  const ushort* pl = helo + (size_t)s * KPAD;
  float x[5];
  float ss = 0.f;
#pragma unroll
  for (int q = 0; q < 5; ++q) {
    int d = lane + q * 64;
    x[q] = bf2f(ph[d]) + bf2f(pl[d]);
    ss += x[q] * x[q];
  }
#pragma unroll
  for (int off = 32; off > 0; off >>= 1) ss += __shfl_down(ss, off, 64);
  ss = __shfl(ss, 0, 64);
  float inv = 1.f / (sqrtf(ss) + 1e-8f);
  ushort* qh = hnhi + (size_t)s * KPAD;
  ushort* ql = hnlo + (size_t)s * KPAD;
#pragma unroll
  for (int q = 0; q < 5; ++q) {
    int d = lane + q * 64;
    float v = x[q] * inv;
    ushort h = f2bf(v);
    qh[d] = h;
    ql[d] = f2bf(v - bf2f(h));
  }
}

// --- K5: cost as gathered MFMA GEMM (hn·hn^T) + fused exp, wave = 32x32 ----
__global__ __launch_bounds__(256) void k_cost_mfma(
    const ushort* __restrict__ hnhi, const ushort* __restrict__ hnlo,
    const int* __restrict__ ridx, const int* __restrict__ cidx,
    const int* __restrict__ rlen, const int* __restrict__ clen,
    float* __restrict__ Kmat) {
  int b = blockIdx.z;
  int r0 = blockIdx.x * 64, c0 = blockIdx.y * 64;
  int rl = rlen[b], cl = clen[b];
  float* Kg = Kmat + (size_t)b * NMAX * MMAX;
  int tid = threadIdx.x;
  if (r0 >= rl || c0 >= cl) {
    for (int l = tid; l < 64 * 16; l += 256) {
      int i = l >> 4, j = (l & 15) << 2;
      *(float4*)&Kg[(size_t)(r0 + i) * MMAX + c0 + j] =
          make_float4(0.f, 0.f, 0.f, 0.f);
    }
    return;
  }
  __shared__ int rix[64], cix[64];
  __shared__ __align__(16) ushort lds[4][64][40];  // Rhi,Rlo,Chi,Clo
  if (tid < 64) rix[tid] = ridx[b * NMAX + r0 + tid];
  else if (tid < 128) cix[tid - 64] = cidx[b * MMAX + c0 + tid - 64];
  __syncthreads();
  int row = tid >> 2, ch = tid & 3;
  const ushort* pRh = hnhi + (size_t)rix[row] * KPAD + ch * 8;
  const ushort* pRl = hnlo + (size_t)rix[row] * KPAD + ch * 8;
  const ushort* pCh = hnhi + (size_t)cix[row] * KPAD + ch * 8;
  const ushort* pCl = hnlo + (size_t)cix[row] * KPAD + ch * 8;
  uint4 rRh, rRl, rCh, rCl;
  auto ld = [&](int c) {
    int o = c * 32;
    rRh = *(const uint4*)(pRh + o);
    rRl = *(const uint4*)(pRl + o);
    rCh = *(const uint4*)(pCh + o);
    rCl = *(const uint4*)(pCl + o);
  };
  auto st = [&]() {
    *(uint4*)&lds[0][row][ch * 8] = rRh;
    *(uint4*)&lds[1][row][ch * 8] = rRl;
    *(uint4*)&lds[2][row][ch * 8] = rCh;
    *(uint4*)&lds[3][row][ch * 8] = rCl;
  };
  int w = tid >> 6, lane = tid & 63;
  int q = lane >> 4, l16 = lane & 15;
  int mh = w >> 1, nh = w & 1;
  f32x4 zf = {0.f, 0.f, 0.f, 0.f};
  f32x4 acc[2][2];
#pragma unroll
  for (int s = 0; s < 2; ++s)
#pragma unroll
    for (int t = 0; t < 2; ++t) acc[s][t] = zf;
  ld(0); st(); __syncthreads();
  for (int c = 0; c < 10; ++c) {
    if (c < 9) ld(c + 1);
    bf16x8 ah0 = *(const bf16x8*)&lds[0][mh * 32 + l16][q * 8];
    bf16x8 ah1 = *(const bf16x8*)&lds[0][mh * 32 + 16 + l16][q * 8];
    bf16x8 al0 = *(const bf16x8*)&lds[1][mh * 32 + l16][q * 8];
    bf16x8 al1 = *(const bf16x8*)&lds[1][mh * 32 + 16 + l16][q * 8];
#pragma unroll
    for (int t = 0; t < 2; ++t) {
      int brow = nh * 32 + t * 16 + l16;
      bf16x8 bh = *(const bf16x8*)&lds[2][brow][q * 8];
      bf16x8 bl = *(const bf16x8*)&lds[3][brow][q * 8];
      acc[0][t] = __builtin_amdgcn_mfma_f32_16x16x32_bf16(ah0, bh, acc[0][t], 0, 0, 0);
      acc[0][t] = __builtin_amdgcn_mfma_f32_16x16x32_bf16(ah0, bl, acc[0][t], 0, 0, 0);
      acc[0][t] = __builtin_amdgcn_mfma_f32_16x16x32_bf16(al0, bh, acc[0][t], 0, 0, 0);
      acc[1][t] = __builtin_amdgcn_mfma_f32_16x16x32_bf16(ah1, bh, acc[1][t], 0, 0, 0);
      acc[1][t] = __builtin_amdgcn_mfma_f32_16x16x32_bf16(ah1, bl, acc[1][t], 0, 0, 0);
      acc[1][t] = __builtin_amdgcn_mfma_f32_16x16x32_bf16(al1, bh, acc[1][t], 0, 0, 0);
    }
    __syncthreads();
    if (c < 9) st();
    __syncthreads();
  }
#pragma unroll
  for (int t = 0; t < 2; ++t) {
    int n = c0 + nh * 32 + t * 16 + l16;
#pragma unroll
    for (int s = 0; s < 2; ++s) {
#pragma unroll
      for (int r = 0; r < 4; ++r) {
        int m = r0 + mh * 32 + s * 16 + q * 4 + r;
        float kv = (m < rl && n < cl) ? expf((acc[s][t][r] - 1.f) / EPSR) : 0.f;
        Kg[(size_t)m * MMAX + n] = kv;
      }
    }
  }
}

// --------- K6: Sinkhorn, K held in VGPRs (kr row / kt col slices) ----------
__global__ __launch_bounds__(512) void k_sinkhorn(
    float* __restrict__ Kmat, const int* __restrict__ rlen,
    const int* __restrict__ clen) {
  __shared__ __align__(16) float vq[4][36];
  __shared__ __align__(16) float uq[4][36];
  int b = blockIdx.x;
  int tid = threadIdx.x;
  int n = tid >> 2, q = tid & 3;
  int rl = rlen[b], cl = clen[b];
  float* Kg = Kmat + (size_t)b * NMAX * MMAX;
  float kr[32], kt[32];
  const float4* Kg4 = (const float4*)(Kg + (size_t)n * MMAX + 32 * q);
#pragma unroll
  for (int t = 0; t < 8; ++t) *(float4*)&kr[4 * t] = Kg4[t];
#pragma unroll
  for (int j = 0; j < 32; ++j) kt[j] = Kg[(size_t)(32 * q + j) * MMAX + n];
  if (tid < 128) vq[tid >> 5][tid & 31] = (tid < cl) ? 1.f : 0.f;
  float av = (n < rl) ? 1.f / (float)rl : 0.f;
  float bv = (n < cl) ? 1.f / (float)cl : 0.f;
  float un = 0.f;
  __syncthreads();
  for (int it = 0; it < SITERS; ++it) {
    float s = 0.f;
#pragma unroll
    for (int t = 0; t < 8; ++t) {
      float4 vv = *(const float4*)&vq[q][4 * t];
      s += kr[4 * t + 0] * vv.x + kr[4 * t + 1] * vv.y +
           kr[4 * t + 2] * vv.z + kr[4 * t + 3] * vv.w;
    }
    s += __shfl_xor(s, 1, 64);
    s += __shfl_xor(s, 2, 64);
    un = (n < rl) ? av / s : 0.f;
    if (q == 0) uq[n >> 5][n & 31] = un;
    __syncthreads();
    float s2 = 0.f;
#pragma unroll
    for (int t = 0; t < 8; ++t) {
      float4 uu = *(const float4*)&uq[q][4 * t];
      s2 += kt[4 * t + 0] * uu.x + kt[4 * t + 1] * uu.y +
            kt[4 * t + 2] * uu.z + kt[4 * t + 3] * uu.w;
    }
    s2 += __shfl_xor(s2, 1, 64);
    s2 += __shfl_xor(s2, 2, 64);
    float vm = (n < cl) ? bv / s2 : 0.f;
    if (q == 0) vq[n >> 5][n & 31] = vm;
    __syncthreads();
  }
  float4* Pg4 = (float4*)(Kg + (size_t)n * MMAX + 32 * q);
#pragma unroll
  for (int t = 0; t < 8; ++t) {
    float4 vv = *(const float4*)&vq[q][4 * t];
    float4 p;
    p.x = un * kr[4 * t + 0] * vv.x;
    p.y = un * kr[4 * t + 1] * vv.y;
    p.z = un * kr[4 * t + 2] * vv.z;
    p.w = un * kr[4 * t + 3] * vv.w;
    Pg4[t] = p;
  }
}

// ---- K7: attend + compare + masked sum, c-paired (128 cols/block) ---------
template <int SIDE>
__global__ __launch_bounds__(256) void k_att_cmp(
    const float* __restrict__ P, const float* __restrict__ HcB,
    const int* __restrict__ idx_main, const int* __restrict__ idx_other,
    const int* __restrict__ len_main, const int* __restrict__ len_other,
    const float* __restrict__ bc, float* __restrict__ outacc) {
  int b = blockIdx.y;
  int c0 = blockIdx.x * 128;
  int lm = len_main[b], lo = len_other[b];
  __shared__ __align__(16) float smem[2][3][16][68];  // [buf][P|G0|G1]
  __shared__ int iox[NMAX];
  __shared__ int imx[NMAX];
  int tid = threadIdx.x, tx = tid & 15, ty = tid >> 4;
  int jj = tid & 63, kq = tid >> 6;
  if (tid < 128) iox[tid] = idx_other[b * NMAX + tid];
  else imx[tid - 128] = idx_main[b * NMAX + tid - 128];
  __syncthreads();
  const float* Pb = P + (size_t)b * NMAX * MMAX;
  bool cok0 = (c0 + jj) < HDIM;
  bool cok1 = (c0 + 64 + jj) < HDIM;
  int nkc = (lo + 15) >> 4;
  int nmt = (lm + 63) >> 6;
  float pR[4], gR[2][4];
  auto loadPG = [&](int mt, int kc) {
    int m0 = mt * 64, k0 = kc * 16;
    if (SIDE == 0) {
#pragma unroll
      for (int p = 0; p < 4; ++p)
        pR[p] = Pb[(size_t)(m0 + ty + p * 16) * MMAX + k0 + tx];
    } else {
#pragma unroll
      for (int p = 0; p < 4; ++p)
        pR[p] = Pb[(size_t)(k0 + kq + p * 4) * MMAX + m0 + jj];
    }
#pragma unroll
    for (int p = 0; p < 4; ++p) {
      int row = iox[k0 + kq + p * 4];
      const float* base = HcB + (size_t)row * 600 + 300 + c0 + jj;
      gR[0][p] = cok0 ? base[0] : 0.f;
      gR[1][p] = cok1 ? base[64] : 0.f;
    }
  };
  auto storePG = [&](int buf) {
    if (SIDE == 0) {
#pragma unroll
      for (int p = 0; p < 4; ++p) smem[buf][0][tx][ty + p * 16] = pR[p];
    } else {
#pragma unroll
      for (int p = 0; p < 4; ++p) smem[buf][0][kq + p * 4][jj] = pR[p];
    }
#pragma unroll
    for (int p = 0; p < 4; ++p) {
      smem[buf][1][kq + p * 4][jj] = gR[0][p];
      smem[buf][2][kq + p * 4][jj] = gR[1][p];
    }
  };
  float colsum[8] = {0.f, 0.f, 0.f, 0.f, 0.f, 0.f, 0.f, 0.f};
  loadPG(0, 0);
  storePG(0);
  __syncthreads();
  int cur = 0;
  for (int mt = 0; mt < nmt; ++mt) {
    float acc[4][8] = {};
    for (int kc = 0; kc < nkc; ++kc) {
      bool last = (mt == nmt - 1) && (kc == nkc - 1);
      if (!last) {
        int nm = (kc + 1 < nkc) ? mt : mt + 1;
        int nk = (kc + 1 < nkc) ? kc + 1 : 0;
        loadPG(nm, nk);
      }
#pragma unroll
      for (int kk = 0; kk < 16; ++kk) {
        float4 av = *(const float4*)&smem[cur][0][kk][ty * 4];
        float4 g0 = *(const float4*)&smem[cur][1][kk][tx * 4];
        float4 g1 = *(const float4*)&smem[cur][2][kk][tx * 4];
        float a[4] = {av.x, av.y, av.z, av.w};
        float gg[8] = {g0.x, g0.y, g0.z, g0.w, g1.x, g1.y, g1.z, g1.w};
#pragma unroll
        for (int i = 0; i < 4; ++i)
#pragma unroll
          for (int j = 0; j < 8; ++j) acc[i][j] += a[i] * gg[j];
      }
      if (!last) storePG(cur ^ 1);
      __syncthreads();
      cur ^= 1;
    }
#pragma unroll
    for (int i = 0; i < 4; ++i) {
      int mi = mt * 64 + ty * 4 + i;
      if (mi >= lm) continue;
      int hrow = imx[mi];
#pragma unroll
      for (int g = 0; g < 2; ++g) {
#pragma unroll
        for (int j = 0; j < 4; ++j) {
          int col = c0 + g * 64 + tx * 4 + j;
          if (col >= HDIM) continue;
          float y = acc[i][g * 4 + j] + HcB[(size_t)hrow * 600 + col] + bc[col];
          colsum[g * 4 + j] += y > 0.f ? y : 0.f;
        }
      }
    }
  }
  __syncthreads();
  float(*red)[68] = (float(*)[68]) & smem[0][0][0][0];
#pragma unroll
  for (int g = 0; g < 2; ++g) {
#pragma unroll
    for (int j = 0; j < 4; ++j) red[ty][tx * 4 + j] = colsum[g * 4 + j];
    __syncthreads();
    if (tid < 64) {
      float s = 0.f;
#pragma unroll
      for (int r = 0; r < 16; ++r) s += red[r][tid];
      int col = c0 + g * 64 + tid;
      if (col < HDIM) outacc[(size_t)b * HDIM + col] = s;
    }
    __syncthreads();
  }
}

// ---------------- K8: classifier head -> out [B,2] -------------------------
__global__ __launch_bounds__(320) void k_cls(
    const float* __restrict__ cr, const float* __restrict__ cc,
    const float* __restrict__ Wcls, const float* __restrict__ bcls,
    const float* __restrict__ Wout, const float* __restrict__ bout,
    float* __restrict__ out) {
  __shared__ __align__(16) float cz[2 * HDIM];
  __shared__ float zz[HDIM];
  int b = blockIdx.x, tid = threadIdx.x;
  if (tid < HDIM) {
    cz[tid] = cr[(size_t)b * HDIM + tid];
    cz[HDIM + tid] = cc[(size_t)b * HDIM + tid];
  }
  __syncthreads();
  if (tid < HDIM) {
    float acc = bcls[tid];
    for (int k4 = 0; k4 < 2 * HDIM; k4 += 4) {
      float4 c = *(const float4*)&cz[k4];
      acc += c.x * Wcls[(size_t)(k4 + 0) * HDIM + tid] +
             c.y * Wcls[(size_t)(k4 + 1) * HDIM + tid] +
             c.z * Wcls[(size_t)(k4 + 2) * HDIM + tid] +
             c.w * Wcls[(size_t)(k4 + 3) * HDIM + tid];
    }
    zz[tid] = acc > 0.f ? acc : 0.f;
  }
  __syncthreads();
  int o = tid >> 6, lane = tid & 63;
  if (o < 2) {
    float p = 0.f;
    for (int j = lane; j < HDIM; j += 64) p += zz[j] * Wout[(size_t)j * 2 + o];
#pragma unroll
    for (int off = 32; off > 0; off >>= 1) p += __shfl_down(p, off, 64);
    if (lane == 0) out[b * 2 + o] = p + bout[o];
  }
}

extern "C" void kernel_launch(void* const* d_in, const int* in_sizes, int n_in,
                              void* d_out, int out_size, void* d_ws, size_t ws_size,
                              hipStream_t stream) {
  (void)in_sizes; (void)n_in; (void)out_size; (void)ws_size;
  const int* data = (const int*)d_in[0];
  const int* row_idx = (const int*)d_in[1];
  const int* col_idx = (const int*)d_in[2];
  const int* row_len = (const int*)d_in[3];
  const int* col_len = (const int*)d_in[4];
  const float* emb = (const float*)d_in[5];
  const float* W1 = (const float*)d_in[6];
  const float* b1 = (const float*)d_in[7];
  const float* W2 = (const float*)d_in[8];
  const float* b2 = (const float*)d_in[9];
  const float* Wc = (const float*)d_in[10];
  const float* bc = (const float*)d_in[11];
  const float* Wcls = (const float*)d_in[12];
  const float* bcls = (const float*)d_in[13];
  const float* Wout = (const float*)d_in[14];
  const float* bout = (const float*)d_in[15];
  float* out = (float*)d_out;

  char* wp = (char*)d_ws;
  auto carve = [&](size_t bytes) {
    char* p = wp; wp += (bytes + 255) & ~(size_t)255; return p;
  };
  ushort* enchi = (ushort*)carve((size_t)NS * KPAD * 2);
  ushort* enclo = (ushort*)carve((size_t)NS * KPAD * 2);
  ushort* h1hi = (ushort*)carve((size_t)NS * KPAD * 2);
  ushort* h1lo = (ushort*)carve((size_t)NS * KPAD * 2);
  ushort* hehi = (ushort*)carve((size_t)NS * KPAD * 2);
  ushort* helo = (ushort*)carve((size_t)NS * KPAD * 2);
  ushort* hnhi = (ushort*)carve((size_t)NS * KPAD * 2);
  ushort* hnlo = (ushort*)carve((size_t)NS * KPAD * 2);
  ushort* W1hi = (ushort*)carve((size_t)NPADW * KPAD * 2);
  ushort* W1lo = (ushort*)carve((size_t)NPADW * KPAD * 2);
  ushort* W2hi = (ushort*)carve((size_t)NPADW * KPAD * 2);
  ushort* W2lo = (ushort*)carve((size_t)NPADW * KPAD * 2);
  ushort* Wchi = (ushort*)carve((size_t)640 * KPAD * 2);
  ushort* Wclo = (ushort*)carve((size_t)640 * KPAD * 2);
  float* HcB = (float*)carve((size_t)NS * 600 * 4);
  float* Km = (float*)carve((size_t)BB * NMAX * MMAX * 4);
  float* cr = (float*)carve((size_t)BB * HDIM * 4);
  float* cc = (float*)carve((size_t)BB * HDIM * 4);

  int gM = (NS + 63) / 64;  // 157
  int cvtTotal = 2 * NPADW * KPAD + 640 * KPAD;

  k_embed<<<NS, 256, 0, stream>>>(data, emb, enchi, enclo);
  k_cvt_all<<<(cvtTotal + 255) / 256, 256, 0, stream>>>(
      W1, W2, Wc, W1hi, W1lo, W2hi, W2lo, Wchi, Wclo);
  k_gemm_mfma<<<dim3(gM, 3), 256, 0, stream>>>(
      enchi, enclo, W1hi, W1lo, b1, NS, HDIM, 1, nullptr, h1hi, h1lo);
  k_gemm_mfma<<<dim3(gM, 3), 256, 0, stream>>>(
      h1hi, h1lo, W2hi, W2lo, b2, NS, HDIM, 1, nullptr, hehi, helo);
  k_norm_split<<<(NS + 3) / 4, 256, 0, stream>>>(hehi, helo, hnhi, hnlo);
  k_gemm_mfma<<<dim3(gM, 5), 256, 0, stream>>>(
      hehi, helo, Wchi, Wclo, nullptr, NS, 2 * HDIM, 0, HcB, nullptr, nullptr);
  k_cost_mfma<<<dim3(2, 2, BB), 256, 0, stream>>>(hnhi, hnlo, row_idx, col_idx,
                                                  row_len, col_len, Km);
  k_sinkhorn<<<BB, 512, 0, stream>>>(Km, row_len, col_len);
  k_att_cmp<0><<<dim3(3, BB), 256, 0, stream>>>(
      Km, HcB, row_idx, col_idx, row_len, col_len, bc, cr);
  k_att_cmp<1><<<dim3(3, BB), 256, 0, stream>>>(
      Km, HcB, col_idx, row_idx, col_len, row_len, bc, cc);
  k_cls<<<BB, 320, 0, stream>>>(cr, cc, Wcls, bcls, Wout, bout, out);
}

// Round 11
// 418.511 us; speedup vs baseline: 1.1485x; 1.1485x over previous
//
#include <hip/hip_runtime.h>
#include <math.h>

#define NS 10000
#define LSEQ 32
#define DDIM 300
#define HDIM 300
#define BB 256
#define NMAX 128
#define MMAX 128
#define EPSR 0.1f
#define SITERS 50
#define KPAD 320
#define NPADW 384

typedef __attribute__((ext_vector_type(8))) short bf16x8;
typedef __attribute__((ext_vector_type(4))) float f32x4;

__device__ __forceinline__ ushort f2bf(float x) {
  union { float f; unsigned u; } c; c.f = x;
  unsigned r = (c.u + 0x7fffu + ((c.u >> 16) & 1u)) >> 16;
  return (ushort)r;
}
__device__ __forceinline__ float bf2f(ushort h) {
  union { unsigned u; float f; } c; c.u = ((unsigned)h) << 16;
  return c.f;
}

// ------- K1: embedding + masked mean pool -> enc hi/lo [NS][KPAD] bf16 -----
__global__ __launch_bounds__(256) void k_embed(const int* __restrict__ data,
                                               const float* __restrict__ emb,
                                               ushort* __restrict__ enchi,
                                               ushort* __restrict__ enclo) {
  __shared__ int ids[LSEQ];
  __shared__ __align__(16) float4 part[3][76];
  int s = blockIdx.x;
  int tid = threadIdx.x;
  if (tid < LSEQ) ids[tid] = data[s * LSEQ + tid];
  __syncthreads();
  int cnt = 0;
#pragma unroll
  for (int t = 0; t < LSEQ; ++t) cnt += (ids[t] != 0) ? 1 : 0;
  int g = tid / 75, d = tid - g * 75;
  const float4* emb4 = (const float4*)emb;
  if (g < 3) {
    float4 acc = make_float4(0.f, 0.f, 0.f, 0.f);
    for (int t = g; t < LSEQ; t += 3) {
      int id = ids[t];
      if (id != 0) {
        float4 e = emb4[(size_t)id * 75 + d];
        acc.x += e.x; acc.y += e.y; acc.z += e.z; acc.w += e.w;
      }
    }
    part[g][d] = acc;
  }
  __syncthreads();
  if (g == 0) {
    float4 a = part[0][d], b = part[1][d], c = part[2][d];
    float inv = 1.f / (float)(cnt > 0 ? cnt : 1);
    float v[4] = {(a.x + b.x + c.x) * inv, (a.y + b.y + c.y) * inv,
                  (a.z + b.z + c.z) * inv, (a.w + b.w + c.w) * inv};
    ushort4 h, l;
    h.x = f2bf(v[0]); l.x = f2bf(v[0] - bf2f(h.x));
    h.y = f2bf(v[1]); l.y = f2bf(v[1] - bf2f(h.y));
    h.z = f2bf(v[2]); l.z = f2bf(v[2] - bf2f(h.z));
    h.w = f2bf(v[3]); l.w = f2bf(v[3] - bf2f(h.w));
    *(ushort4*)&enchi[(size_t)s * KPAD + d * 4] = h;
    *(ushort4*)&enclo[(size_t)s * KPAD + d * 4] = l;
  } else if (g == 1 && d < 5) {
    ushort4 z; z.x = z.y = z.z = z.w = 0;
    *(ushort4*)&enchi[(size_t)s * KPAD + 300 + d * 4] = z;
    *(ushort4*)&enclo[(size_t)s * KPAD + 300 + d * 4] = z;
  }
}

// ------- K2: all weight converts in one dispatch ---------------------------
__global__ __launch_bounds__(256) void k_cvt_all(
    const float* __restrict__ W1, const float* __restrict__ W2,
    const float* __restrict__ Wc, ushort* __restrict__ W1hi,
    ushort* __restrict__ W1lo, ushort* __restrict__ W2hi,
    ushort* __restrict__ W2lo, ushort* __restrict__ Wchi,
    ushort* __restrict__ Wclo) {
  int i = blockIdx.x * 256 + threadIdx.x;
  const int SA = NPADW * KPAD;
  const int SC = 640 * KPAD;
  float v = 0.f;
  ushort *ph, *pl;
  int idx;
  if (i < SA) {
    idx = i;
    int n = idx / KPAD, k = idx - n * KPAD;
    if (n < HDIM && k < DDIM) v = W1[(size_t)k * HDIM + n];
    ph = W1hi; pl = W1lo;
  } else if (i < 2 * SA) {
    idx = i - SA;
    int n = idx / KPAD, k = idx - n * KPAD;
    if (n < HDIM && k < HDIM) v = W2[(size_t)k * HDIM + n];
    ph = W2hi; pl = W2lo;
  } else if (i < 2 * SA + SC) {
    idx = i - 2 * SA;
    int n = idx / KPAD, k = idx - n * KPAD;
    if (k < HDIM && n < 2 * HDIM)
      v = (n < HDIM) ? Wc[(size_t)k * HDIM + n]
                     : Wc[(size_t)(HDIM + k) * HDIM + (n - HDIM)];
    ph = Wchi; pl = Wclo;
  } else {
    return;
  }
  ushort h = f2bf(v);
  ph[idx] = h;
  pl[idx] = f2bf(v - bf2f(h));
}

// ------- K3: MFMA GEMM, hi/lo 3-term, 64x128 tile, wave = 32x64 ------------
__global__ __launch_bounds__(256) void k_gemm_mfma(
    const ushort* __restrict__ Ahi, const ushort* __restrict__ Alo,
    const ushort* __restrict__ BhiT, const ushort* __restrict__ BloT,
    const float* __restrict__ bias, int M, int N, int relu,
    float* __restrict__ Cf, ushort* __restrict__ Chi,
    ushort* __restrict__ Clo) {
  __shared__ __align__(16) ushort ldsA[2][64][40];
  __shared__ __align__(16) ushort ldsB[2][128][40];
  int tid = threadIdx.x;
  int m0 = blockIdx.x * 64, n0 = blockIdx.y * 128;
  int rowA = tid >> 2, chA = (tid & 3) * 8;
  int rowB = tid >> 1, chB = (tid & 1) * 16;
  bool mok = (m0 + rowA) < M;
  const ushort* pAh = Ahi + (size_t)(m0 + rowA) * KPAD + chA;
  const ushort* pAl = Alo + (size_t)(m0 + rowA) * KPAD + chA;
  const ushort* pBh = BhiT + (size_t)(n0 + rowB) * KPAD + chB;
  const ushort* pBl = BloT + (size_t)(n0 + rowB) * KPAD + chB;
  uint4 rAh, rAl, rBh0, rBh1, rBl0, rBl1;
  uint4 z4; z4.x = z4.y = z4.z = z4.w = 0;
  auto ld = [&](int c) {
    int o = c * 32;
    rAh = mok ? *(const uint4*)(pAh + o) : z4;
    rAl = mok ? *(const uint4*)(pAl + o) : z4;
    rBh0 = *(const uint4*)(pBh + o);
    rBh1 = *(const uint4*)(pBh + o + 8);
    rBl0 = *(const uint4*)(pBl + o);
    rBl1 = *(const uint4*)(pBl + o + 8);
  };
  auto st = [&]() {
    *(uint4*)&ldsA[0][rowA][chA] = rAh;
    *(uint4*)&ldsA[1][rowA][chA] = rAl;
    *(uint4*)&ldsB[0][rowB][chB] = rBh0;
    *(uint4*)&ldsB[0][rowB][chB + 8] = rBh1;
    *(uint4*)&ldsB[1][rowB][chB] = rBl0;
    *(uint4*)&ldsB[1][rowB][chB + 8] = rBl1;
  };
  int w = tid >> 6, lane = tid & 63;
  int q = lane >> 4, l16 = lane & 15;
  int mh = w >> 1, nh = w & 1;
  f32x4 zf = {0.f, 0.f, 0.f, 0.f};
  f32x4 acc[2][4];
#pragma unroll
  for (int s = 0; s < 2; ++s)
#pragma unroll
    for (int t = 0; t < 4; ++t) acc[s][t] = zf;
  ld(0); st(); __syncthreads();
  for (int c = 0; c < 10; ++c) {
    if (c < 9) ld(c + 1);
    bf16x8 ah0 = *(const bf16x8*)&ldsA[0][mh * 32 + l16][q * 8];
    bf16x8 ah1 = *(const bf16x8*)&ldsA[0][mh * 32 + 16 + l16][q * 8];
    bf16x8 al0 = *(const bf16x8*)&ldsA[1][mh * 32 + l16][q * 8];
    bf16x8 al1 = *(const bf16x8*)&ldsA[1][mh * 32 + 16 + l16][q * 8];
#pragma unroll
    for (int t = 0; t < 4; ++t) {
      int brow = nh * 64 + t * 16 + l16;
      bf16x8 bh = *(const bf16x8*)&ldsB[0][brow][q * 8];
      bf16x8 bl = *(const bf16x8*)&ldsB[1][brow][q * 8];
      acc[0][t] = __builtin_amdgcn_mfma_f32_16x16x32_bf16(ah0, bh, acc[0][t], 0, 0, 0);
      acc[0][t] = __builtin_amdgcn_mfma_f32_16x16x32_bf16(ah0, bl, acc[0][t], 0, 0, 0);
      acc[0][t] = __builtin_amdgcn_mfma_f32_16x16x32_bf16(al0, bh, acc[0][t], 0, 0, 0);
      acc[1][t] = __builtin_amdgcn_mfma_f32_16x16x32_bf16(ah1, bh, acc[1][t], 0, 0, 0);
      acc[1][t] = __builtin_amdgcn_mfma_f32_16x16x32_bf16(ah1, bl, acc[1][t], 0, 0, 0);
      acc[1][t] = __builtin_amdgcn_mfma_f32_16x16x32_bf16(al1, bh, acc[1][t], 0, 0, 0);
    }
    __syncthreads();
    if (c < 9) st();
    __syncthreads();
  }
#pragma unroll
  for (int t = 0; t < 4; ++t) {
    int n = n0 + nh * 64 + t * 16 + l16;
    bool nin = n < N;
    float bz = (bias && nin) ? bias[n] : 0.f;
#pragma unroll
    for (int s = 0; s < 2; ++s) {
#pragma unroll
      for (int r = 0; r < 4; ++r) {
        int m = m0 + mh * 32 + s * 16 + q * 4 + r;
        if (m >= M) continue;
        float v = acc[s][t][r] + bz;
        if (relu) v = v > 0.f ? v : 0.f;
        if (Cf && nin) Cf[(size_t)m * N + n] = v;
        if (Chi && n < KPAD) {
          ushort h = 0, l = 0;
          if (nin) { h = f2bf(v); l = f2bf(v - bf2f(h)); }
          Chi[(size_t)m * KPAD + n] = h;
          Clo[(size_t)m * KPAD + n] = l;
        }
      }
    }
  }
}

// --- K4: normalize henc (hi/lo) -> hn hi/lo [NS][KPAD] (unit rows) ---------
__global__ __launch_bounds__(256) void k_norm_split(
    const ushort* __restrict__ hehi, const ushort* __restrict__ helo,
    ushort* __restrict__ hnhi, ushort* __restrict__ hnlo) {
  int s = blockIdx.x * 4 + (threadIdx.x >> 6);
  int lane = threadIdx.x & 63;
  if (s >= NS) return;
  const ushort* ph = hehi + (size_t)s * KPAD;
  const ushort* pl = helo + (size_t)s * KPAD;
  float x[5];
  float ss = 0.f;
#pragma unroll
  for (int q = 0; q < 5; ++q) {
    int d = lane + q * 64;
    x[q] = bf2f(ph[d]) + bf2f(pl[d]);
    ss += x[q] * x[q];
  }
#pragma unroll
  for (int off = 32; off > 0; off >>= 1) ss += __shfl_down(ss, off, 64);
  ss = __shfl(ss, 0, 64);
  float inv = 1.f / (sqrtf(ss) + 1e-8f);
  ushort* qh = hnhi + (size_t)s * KPAD;
  ushort* ql = hnlo + (size_t)s * KPAD;
#pragma unroll
  for (int q = 0; q < 5; ++q) {
    int d = lane + q * 64;
    float v = x[q] * inv;
    ushort h = f2bf(v);
    qh[d] = h;
    ql[d] = f2bf(v - bf2f(h));
  }
}

// --- K5: cost as gathered MFMA GEMM (hn·hn^T) + fused exp, wave = 32x32 ----
__global__ __launch_bounds__(256) void k_cost_mfma(
    const ushort* __restrict__ hnhi, const ushort* __restrict__ hnlo,
    const int* __restrict__ ridx, const int* __restrict__ cidx,
    const int* __restrict__ rlen, const int* __restrict__ clen,
    float* __restrict__ Kmat) {
  int b = blockIdx.z;
  int r0 = blockIdx.x * 64, c0 = blockIdx.y * 64;
  int rl = rlen[b], cl = clen[b];
  float* Kg = Kmat + (size_t)b * NMAX * MMAX;
  int tid = threadIdx.x;
  if (r0 >= rl || c0 >= cl) {
    for (int l = tid; l < 64 * 16; l += 256) {
      int i = l >> 4, j = (l & 15) << 2;
      *(float4*)&Kg[(size_t)(r0 + i) * MMAX + c0 + j] =
          make_float4(0.f, 0.f, 0.f, 0.f);
    }
    return;
  }
  __shared__ int rix[64], cix[64];
  __shared__ __align__(16) ushort lds[4][64][40];  // Rhi,Rlo,Chi,Clo
  if (tid < 64) rix[tid] = ridx[b * NMAX + r0 + tid];
  else if (tid < 128) cix[tid - 64] = cidx[b * MMAX + c0 + tid - 64];
  __syncthreads();
  int row = tid >> 2, ch = tid & 3;
  const ushort* pRh = hnhi + (size_t)rix[row] * KPAD + ch * 8;
  const ushort* pRl = hnlo + (size_t)rix[row] * KPAD + ch * 8;
  const ushort* pCh = hnhi + (size_t)cix[row] * KPAD + ch * 8;
  const ushort* pCl = hnlo + (size_t)cix[row] * KPAD + ch * 8;
  uint4 rRh, rRl, rCh, rCl;
  auto ld = [&](int c) {
    int o = c * 32;
    rRh = *(const uint4*)(pRh + o);
    rRl = *(const uint4*)(pRl + o);
    rCh = *(const uint4*)(pCh + o);
    rCl = *(const uint4*)(pCl + o);
  };
  auto st = [&]() {
    *(uint4*)&lds[0][row][ch * 8] = rRh;
    *(uint4*)&lds[1][row][ch * 8] = rRl;
    *(uint4*)&lds[2][row][ch * 8] = rCh;
    *(uint4*)&lds[3][row][ch * 8] = rCl;
  };
  int w = tid >> 6, lane = tid & 63;
  int q = lane >> 4, l16 = lane & 15;
  int mh = w >> 1, nh = w & 1;
  f32x4 zf = {0.f, 0.f, 0.f, 0.f};
  f32x4 acc[2][2];
#pragma unroll
  for (int s = 0; s < 2; ++s)
#pragma unroll
    for (int t = 0; t < 2; ++t) acc[s][t] = zf;
  ld(0); st(); __syncthreads();
  for (int c = 0; c < 10; ++c) {
    if (c < 9) ld(c + 1);
    bf16x8 ah0 = *(const bf16x8*)&lds[0][mh * 32 + l16][q * 8];
    bf16x8 ah1 = *(const bf16x8*)&lds[0][mh * 32 + 16 + l16][q * 8];
    bf16x8 al0 = *(const bf16x8*)&lds[1][mh * 32 + l16][q * 8];
    bf16x8 al1 = *(const bf16x8*)&lds[1][mh * 32 + 16 + l16][q * 8];
#pragma unroll
    for (int t = 0; t < 2; ++t) {
      int brow = nh * 32 + t * 16 + l16;
      bf16x8 bh = *(const bf16x8*)&lds[2][brow][q * 8];
      bf16x8 bl = *(const bf16x8*)&lds[3][brow][q * 8];
      acc[0][t] = __builtin_amdgcn_mfma_f32_16x16x32_bf16(ah0, bh, acc[0][t], 0, 0, 0);
      acc[0][t] = __builtin_amdgcn_mfma_f32_16x16x32_bf16(ah0, bl, acc[0][t], 0, 0, 0);
      acc[0][t] = __builtin_amdgcn_mfma_f32_16x16x32_bf16(al0, bh, acc[0][t], 0, 0, 0);
      acc[1][t] = __builtin_amdgcn_mfma_f32_16x16x32_bf16(ah1, bh, acc[1][t], 0, 0, 0);
      acc[1][t] = __builtin_amdgcn_mfma_f32_16x16x32_bf16(ah1, bl, acc[1][t], 0, 0, 0);
      acc[1][t] = __builtin_amdgcn_mfma_f32_16x16x32_bf16(al1, bh, acc[1][t], 0, 0, 0);
    }
    __syncthreads();
    if (c < 9) st();
    __syncthreads();
  }
#pragma unroll
  for (int t = 0; t < 2; ++t) {
    int n = c0 + nh * 32 + t * 16 + l16;
#pragma unroll
    for (int s = 0; s < 2; ++s) {
#pragma unroll
      for (int r = 0; r < 4; ++r) {
        int m = r0 + mh * 32 + s * 16 + q * 4 + r;
        float kv = (m < rl && n < cl) ? expf((acc[s][t][r] - 1.f) / EPSR) : 0.f;
        Kg[(size_t)m * MMAX + n] = kv;
      }
    }
  }
}

// --------- K6: Sinkhorn, K held in VGPRs (kr row / kt col slices) ----------
__global__ __launch_bounds__(512) void k_sinkhorn(
    float* __restrict__ Kmat, const int* __restrict__ rlen,
    const int* __restrict__ clen) {
  __shared__ __align__(16) float vq[4][36];
  __shared__ __align__(16) float uq[4][36];
  int b = blockIdx.x;
  int tid = threadIdx.x;
  int n = tid >> 2, q = tid & 3;
  int rl = rlen[b], cl = clen[b];
  float* Kg = Kmat + (size_t)b * NMAX * MMAX;
  float kr[32], kt[32];
  const float4* Kg4 = (const float4*)(Kg + (size_t)n * MMAX + 32 * q);
#pragma unroll
  for (int t = 0; t < 8; ++t) *(float4*)&kr[4 * t] = Kg4[t];
#pragma unroll
  for (int j = 0; j < 32; ++j) kt[j] = Kg[(size_t)(32 * q + j) * MMAX + n];
  if (tid < 128) vq[tid >> 5][tid & 31] = (tid < cl) ? 1.f : 0.f;
  float av = (n < rl) ? 1.f / (float)rl : 0.f;
  float bv = (n < cl) ? 1.f / (float)cl : 0.f;
  float un = 0.f;
  __syncthreads();
  for (int it = 0; it < SITERS; ++it) {
    float s = 0.f;
#pragma unroll
    for (int t = 0; t < 8; ++t) {
      float4 vv = *(const float4*)&vq[q][4 * t];
      s += kr[4 * t + 0] * vv.x + kr[4 * t + 1] * vv.y +
           kr[4 * t + 2] * vv.z + kr[4 * t + 3] * vv.w;
    }
    s += __shfl_xor(s, 1, 64);
    s += __shfl_xor(s, 2, 64);
    un = (n < rl) ? av / s : 0.f;
    if (q == 0) uq[n >> 5][n & 31] = un;
    __syncthreads();
    float s2 = 0.f;
#pragma unroll
    for (int t = 0; t < 8; ++t) {
      float4 uu = *(const float4*)&uq[q][4 * t];
      s2 += kt[4 * t + 0] * uu.x + kt[4 * t + 1] * uu.y +
            kt[4 * t + 2] * uu.z + kt[4 * t + 3] * uu.w;
    }
    s2 += __shfl_xor(s2, 1, 64);
    s2 += __shfl_xor(s2, 2, 64);
    float vm = (n < cl) ? bv / s2 : 0.f;
    if (q == 0) vq[n >> 5][n & 31] = vm;
    __syncthreads();
  }
  float4* Pg4 = (float4*)(Kg + (size_t)n * MMAX + 32 * q);
#pragma unroll
  for (int t = 0; t < 8; ++t) {
    float4 vv = *(const float4*)&vq[q][4 * t];
    float4 p;
    p.x = un * kr[4 * t + 0] * vv.x;
    p.y = un * kr[4 * t + 1] * vv.y;
    p.z = un * kr[4 * t + 2] * vv.z;
    p.w = un * kr[4 * t + 3] * vv.w;
    Pg4[t] = p;
  }
}

// ---- K7: attend + compare + masked sum, prefetch dbuf (64-col blocks) -----
// Reverted to the round-9 shape: grid (5,B), VGPR~56, 4 waves, high block
// count — occupancy beats the P-traffic saved by wider tiles (R10 lesson).
template <int SIDE>
__global__ __launch_bounds__(256) void k_att_cmp(
    const float* __restrict__ P, const float* __restrict__ HcB,
    const int* __restrict__ idx_main, const int* __restrict__ idx_other,
    const int* __restrict__ len_main, const int* __restrict__ len_other,
    const float* __restrict__ bc, float* __restrict__ outacc) {
  int b = blockIdx.y;
  int c0 = blockIdx.x * 64;
  int lm = len_main[b], lo = len_other[b];
  __shared__ __align__(16) float smem[2][2][16][68];  // [buf][P|G]
  __shared__ int iox[NMAX];
  __shared__ int imx[NMAX];
  int tid = threadIdx.x, tx = tid & 15, ty = tid >> 4;
  int jj = tid & 63, kq = tid >> 6;
  if (tid < 128) iox[tid] = idx_other[b * NMAX + tid];
  else imx[tid - 128] = idx_main[b * NMAX + tid - 128];
  __syncthreads();
  const float* Pb = P + (size_t)b * NMAX * MMAX;
  bool cok = (c0 + jj) < HDIM;
  int nkc = (lo + 15) >> 4;
  int nmt = (lm + 63) >> 6;
  float pR[4], gR[4];
  auto loadPG = [&](int mt, int kc) {
    int m0 = mt * 64, k0 = kc * 16;
    if (SIDE == 0) {
#pragma unroll
      for (int p = 0; p < 4; ++p)
        pR[p] = Pb[(size_t)(m0 + ty + p * 16) * MMAX + k0 + tx];
    } else {
#pragma unroll
      for (int p = 0; p < 4; ++p)
        pR[p] = Pb[(size_t)(k0 + kq + p * 4) * MMAX + m0 + jj];
    }
#pragma unroll
    for (int p = 0; p < 4; ++p) {
      int row = iox[k0 + kq + p * 4];
      gR[p] = cok ? HcB[(size_t)row * 600 + 300 + c0 + jj] : 0.f;
    }
  };
  auto storePG = [&](int buf) {
    if (SIDE == 0) {
#pragma unroll
      for (int p = 0; p < 4; ++p) smem[buf][0][tx][ty + p * 16] = pR[p];
    } else {
#pragma unroll
      for (int p = 0; p < 4; ++p) smem[buf][0][kq + p * 4][jj] = pR[p];
    }
#pragma unroll
    for (int p = 0; p < 4; ++p) smem[buf][1][kq + p * 4][jj] = gR[p];
  };
  float colsum[4] = {0.f, 0.f, 0.f, 0.f};
  loadPG(0, 0);
  storePG(0);
  __syncthreads();
  int cur = 0;
  for (int mt = 0; mt < nmt; ++mt) {
    float acc[4][4] = {};
    for (int kc = 0; kc < nkc; ++kc) {
      bool last = (mt == nmt - 1) && (kc == nkc - 1);
      if (!last) {
        int nm = (kc + 1 < nkc) ? mt : mt + 1;
        int nk = (kc + 1 < nkc) ? kc + 1 : 0;
        loadPG(nm, nk);
      }
#pragma unroll
      for (int kk = 0; kk < 16; ++kk) {
        float4 av = *(const float4*)&smem[cur][0][kk][ty * 4];
        float4 gv = *(const float4*)&smem[cur][1][kk][tx * 4];
        float a[4] = {av.x, av.y, av.z, av.w};
        float g[4] = {gv.x, gv.y, gv.z, gv.w};
#pragma unroll
        for (int i = 0; i < 4; ++i)
#pragma unroll
          for (int j = 0; j < 4; ++j) acc[i][j] += a[i] * g[j];
      }
      if (!last) storePG(cur ^ 1);
      __syncthreads();
      cur ^= 1;
    }
#pragma unroll
    for (int i = 0; i < 4; ++i) {
      int mi = mt * 64 + ty * 4 + i;
      if (mi >= lm) continue;
      int hrow = imx[mi];
#pragma unroll
      for (int j = 0; j < 4; ++j) {
        int col = c0 + tx * 4 + j;
        if (col >= HDIM) continue;
        float y = acc[i][j] + HcB[(size_t)hrow * 600 + col] + bc[col];
        colsum[j] += y > 0.f ? y : 0.f;
      }
    }
  }
  __syncthreads();
  float(*red)[68] = (float(*)[68]) & smem[0][0][0][0];
#pragma unroll
  for (int j = 0; j < 4; ++j) red[ty][tx * 4 + j] = colsum[j];
  __syncthreads();
  if (tid < 64) {
    float s = 0.f;
#pragma unroll
    for (int r = 0; r < 16; ++r) s += red[r][tid];
    int col = c0 + tid;
    if (col < HDIM) outacc[(size_t)b * HDIM + col] = s;
  }
}

// ---------------- K8: classifier head -> out [B,2] -------------------------
__global__ __launch_bounds__(320) void k_cls(
    const float* __restrict__ cr, const float* __restrict__ cc,
    const float* __restrict__ Wcls, const float* __restrict__ bcls,
    const float* __restrict__ Wout, const float* __restrict__ bout,
    float* __restrict__ out) {
  __shared__ __align__(16) float cz[2 * HDIM];
  __shared__ float zz[HDIM];
  int b = blockIdx.x, tid = threadIdx.x;
  if (tid < HDIM) {
    cz[tid] = cr[(size_t)b * HDIM + tid];
    cz[HDIM + tid] = cc[(size_t)b * HDIM + tid];
  }
  __syncthreads();
  if (tid < HDIM) {
    float acc = bcls[tid];
    for (int k4 = 0; k4 < 2 * HDIM; k4 += 4) {
      float4 c = *(const float4*)&cz[k4];
      acc += c.x * Wcls[(size_t)(k4 + 0) * HDIM + tid] +
             c.y * Wcls[(size_t)(k4 + 1) * HDIM + tid] +
             c.z * Wcls[(size_t)(k4 + 2) * HDIM + tid] +
             c.w * Wcls[(size_t)(k4 + 3) * HDIM + tid];
    }
    zz[tid] = acc > 0.f ? acc : 0.f;
  }
  __syncthreads();
  int o = tid >> 6, lane = tid & 63;
  if (o < 2) {
    float p = 0.f;
    for (int j = lane; j < HDIM; j += 64) p += zz[j] * Wout[(size_t)j * 2 + o];
#pragma unroll
    for (int off = 32; off > 0; off >>= 1) p += __shfl_down(p, off, 64);
    if (lane == 0) out[b * 2 + o] = p + bout[o];
  }
}

extern "C" void kernel_launch(void* const* d_in, const int* in_sizes, int n_in,
                              void* d_out, int out_size, void* d_ws, size_t ws_size,
                              hipStream_t stream) {
  (void)in_sizes; (void)n_in; (void)out_size; (void)ws_size;
  const int* data = (const int*)d_in[0];
  const int* row_idx = (const int*)d_in[1];
  const int* col_idx = (const int*)d_in[2];
  const int* row_len = (const int*)d_in[3];
  const int* col_len = (const int*)d_in[4];
  const float* emb = (const float*)d_in[5];
  const float* W1 = (const float*)d_in[6];
  const float* b1 = (const float*)d_in[7];
  const float* W2 = (const float*)d_in[8];
  const float* b2 = (const float*)d_in[9];
  const float* Wc = (const float*)d_in[10];
  const float* bc = (const float*)d_in[11];
  const float* Wcls = (const float*)d_in[12];
  const float* bcls = (const float*)d_in[13];
  const float* Wout = (const float*)d_in[14];
  const float* bout = (const float*)d_in[15];
  float* out = (float*)d_out;

  char* wp = (char*)d_ws;
  auto carve = [&](size_t bytes) {
    char* p = wp; wp += (bytes + 255) & ~(size_t)255; return p;
  };
  ushort* enchi = (ushort*)carve((size_t)NS * KPAD * 2);
  ushort* enclo = (ushort*)carve((size_t)NS * KPAD * 2);
  ushort* h1hi = (ushort*)carve((size_t)NS * KPAD * 2);
  ushort* h1lo = (ushort*)carve((size_t)NS * KPAD * 2);
  ushort* hehi = (ushort*)carve((size_t)NS * KPAD * 2);
  ushort* helo = (ushort*)carve((size_t)NS * KPAD * 2);
  ushort* hnhi = (ushort*)carve((size_t)NS * KPAD * 2);
  ushort* hnlo = (ushort*)carve((size_t)NS * KPAD * 2);
  ushort* W1hi = (ushort*)carve((size_t)NPADW * KPAD * 2);
  ushort* W1lo = (ushort*)carve((size_t)NPADW * KPAD * 2);
  ushort* W2hi = (ushort*)carve((size_t)NPADW * KPAD * 2);
  ushort* W2lo = (ushort*)carve((size_t)NPADW * KPAD * 2);
  ushort* Wchi = (ushort*)carve((size_t)640 * KPAD * 2);
  ushort* Wclo = (ushort*)carve((size_t)640 * KPAD * 2);
  float* HcB = (float*)carve((size_t)NS * 600 * 4);
  float* Km = (float*)carve((size_t)BB * NMAX * MMAX * 4);
  float* cr = (float*)carve((size_t)BB * HDIM * 4);
  float* cc = (float*)carve((size_t)BB * HDIM * 4);

  int gM = (NS + 63) / 64;  // 157
  int cvtTotal = 2 * NPADW * KPAD + 640 * KPAD;

  k_embed<<<NS, 256, 0, stream>>>(data, emb, enchi, enclo);
  k_cvt_all<<<(cvtTotal + 255) / 256, 256, 0, stream>>>(
      W1, W2, Wc, W1hi, W1lo, W2hi, W2lo, Wchi, Wclo);
  k_gemm_mfma<<<dim3(gM, 3), 256, 0, stream>>>(
      enchi, enclo, W1hi, W1lo, b1, NS, HDIM, 1, nullptr, h1hi, h1lo);
  k_gemm_mfma<<<dim3(gM, 3), 256, 0, stream>>>(
      h1hi, h1lo, W2hi, W2lo, b2, NS, HDIM, 1, nullptr, hehi, helo);
  k_norm_split<<<(NS + 3) / 4, 256, 0, stream>>>(hehi, helo, hnhi, hnlo);
  k_gemm_mfma<<<dim3(gM, 5), 256, 0, stream>>>(
      hehi, helo, Wchi, Wclo, nullptr, NS, 2 * HDIM, 0, HcB, nullptr, nullptr);
  k_cost_mfma<<<dim3(2, 2, BB), 256, 0, stream>>>(hnhi, hnlo, row_idx, col_idx,
                                                  row_len, col_len, Km);
  k_sinkhorn<<<BB, 512, 0, stream>>>(Km, row_len, col_len);
  k_att_cmp<0><<<dim3(5, BB), 256, 0, stream>>>(
      Km, HcB, row_idx, col_idx, row_len, col_len, bc, cr);
  k_att_cmp<1><<<dim3(5, BB), 256, 0, stream>>>(
      Km, HcB, col_idx, row_idx, col_len, row_len, bc, cc);
  k_cls<<<BB, 320, 0, stream>>>(cr, cc, Wcls, bcls, Wout, bout, out);
}

// Round 12
// 402.885 us; speedup vs baseline: 1.1931x; 1.0388x over previous
//
#include <hip/hip_runtime.h>
#include <math.h>

#define NS 10000
#define LSEQ 32
#define DDIM 300
#define HDIM 300
#define BB 256
#define NMAX 128
#define MMAX 128
#define EPSR 0.1f
#define SITERS 50
#define KPAD 320
#define NPADW 384

typedef __attribute__((ext_vector_type(8))) short bf16x8;
typedef __attribute__((ext_vector_type(4))) float f32x4;

__device__ __forceinline__ ushort f2bf(float x) {
  union { float f; unsigned u; } c; c.f = x;
  unsigned r = (c.u + 0x7fffu + ((c.u >> 16) & 1u)) >> 16;
  return (ushort)r;
}
__device__ __forceinline__ float bf2f(ushort h) {
  union { unsigned u; float f; } c; c.u = ((unsigned)h) << 16;
  return c.f;
}

// ------- K1: embedding + masked mean pool -> enc hi/lo [NS][KPAD] bf16 -----
__global__ __launch_bounds__(256) void k_embed(const int* __restrict__ data,
                                               const float* __restrict__ emb,
                                               ushort* __restrict__ enchi,
                                               ushort* __restrict__ enclo) {
  __shared__ int ids[LSEQ];
  __shared__ __align__(16) float4 part[3][76];
  int s = blockIdx.x;
  int tid = threadIdx.x;
  if (tid < LSEQ) ids[tid] = data[s * LSEQ + tid];
  __syncthreads();
  int cnt = 0;
#pragma unroll
  for (int t = 0; t < LSEQ; ++t) cnt += (ids[t] != 0) ? 1 : 0;
  int g = tid / 75, d = tid - g * 75;
  const float4* emb4 = (const float4*)emb;
  if (g < 3) {
    float4 acc = make_float4(0.f, 0.f, 0.f, 0.f);
    for (int t = g; t < LSEQ; t += 3) {
      int id = ids[t];
      if (id != 0) {
        float4 e = emb4[(size_t)id * 75 + d];
        acc.x += e.x; acc.y += e.y; acc.z += e.z; acc.w += e.w;
      }
    }
    part[g][d] = acc;
  }
  __syncthreads();
  if (g == 0) {
    float4 a = part[0][d], b = part[1][d], c = part[2][d];
    float inv = 1.f / (float)(cnt > 0 ? cnt : 1);
    float v[4] = {(a.x + b.x + c.x) * inv, (a.y + b.y + c.y) * inv,
                  (a.z + b.z + c.z) * inv, (a.w + b.w + c.w) * inv};
    ushort4 h, l;
    h.x = f2bf(v[0]); l.x = f2bf(v[0] - bf2f(h.x));
    h.y = f2bf(v[1]); l.y = f2bf(v[1] - bf2f(h.y));
    h.z = f2bf(v[2]); l.z = f2bf(v[2] - bf2f(h.z));
    h.w = f2bf(v[3]); l.w = f2bf(v[3] - bf2f(h.w));
    *(ushort4*)&enchi[(size_t)s * KPAD + d * 4] = h;
    *(ushort4*)&enclo[(size_t)s * KPAD + d * 4] = l;
  } else if (g == 1 && d < 5) {
    ushort4 z; z.x = z.y = z.z = z.w = 0;
    *(ushort4*)&enchi[(size_t)s * KPAD + 300 + d * 4] = z;
    *(ushort4*)&enclo[(size_t)s * KPAD + 300 + d * 4] = z;
  }
}

// ------- K2: all weight converts in one dispatch ---------------------------
__global__ __launch_bounds__(256) void k_cvt_all(
    const float* __restrict__ W1, const float* __restrict__ W2,
    const float* __restrict__ Wc, ushort* __restrict__ W1hi,
    ushort* __restrict__ W1lo, ushort* __restrict__ W2hi,
    ushort* __restrict__ W2lo, ushort* __restrict__ Wchi,
    ushort* __restrict__ Wclo) {
  int i = blockIdx.x * 256 + threadIdx.x;
  const int SA = NPADW * KPAD;
  const int SC = 640 * KPAD;
  float v = 0.f;
  ushort *ph, *pl;
  int idx;
  if (i < SA) {
    idx = i;
    int n = idx / KPAD, k = idx - n * KPAD;
    if (n < HDIM && k < DDIM) v = W1[(size_t)k * HDIM + n];
    ph = W1hi; pl = W1lo;
  } else if (i < 2 * SA) {
    idx = i - SA;
    int n = idx / KPAD, k = idx - n * KPAD;
    if (n < HDIM && k < HDIM) v = W2[(size_t)k * HDIM + n];
    ph = W2hi; pl = W2lo;
  } else if (i < 2 * SA + SC) {
    idx = i - 2 * SA;
    int n = idx / KPAD, k = idx - n * KPAD;
    if (k < HDIM && n < 2 * HDIM)
      v = (n < HDIM) ? Wc[(size_t)k * HDIM + n]
                     : Wc[(size_t)(HDIM + k) * HDIM + (n - HDIM)];
    ph = Wchi; pl = Wclo;
  } else {
    return;
  }
  ushort h = f2bf(v);
  ph[idx] = h;
  pl[idx] = f2bf(v - bf2f(h));
}

// ------- K3: MFMA GEMM, hi/lo 3-term, 64x128 tile, wave = 32x64 ------------
__global__ __launch_bounds__(256) void k_gemm_mfma(
    const ushort* __restrict__ Ahi, const ushort* __restrict__ Alo,
    const ushort* __restrict__ BhiT, const ushort* __restrict__ BloT,
    const float* __restrict__ bias, int M, int N, int relu,
    float* __restrict__ Cf, ushort* __restrict__ Chi,
    ushort* __restrict__ Clo) {
  __shared__ __align__(16) ushort ldsA[2][64][40];
  __shared__ __align__(16) ushort ldsB[2][128][40];
  int tid = threadIdx.x;
  int m0 = blockIdx.x * 64, n0 = blockIdx.y * 128;
  int rowA = tid >> 2, chA = (tid & 3) * 8;
  int rowB = tid >> 1, chB = (tid & 1) * 16;
  bool mok = (m0 + rowA) < M;
  const ushort* pAh = Ahi + (size_t)(m0 + rowA) * KPAD + chA;
  const ushort* pAl = Alo + (size_t)(m0 + rowA) * KPAD + chA;
  const ushort* pBh = BhiT + (size_t)(n0 + rowB) * KPAD + chB;
  const ushort* pBl = BloT + (size_t)(n0 + rowB) * KPAD + chB;
  uint4 rAh, rAl, rBh0, rBh1, rBl0, rBl1;
  uint4 z4; z4.x = z4.y = z4.z = z4.w = 0;
  auto ld = [&](int c) {
    int o = c * 32;
    rAh = mok ? *(const uint4*)(pAh + o) : z4;
    rAl = mok ? *(const uint4*)(pAl + o) : z4;
    rBh0 = *(const uint4*)(pBh + o);
    rBh1 = *(const uint4*)(pBh + o + 8);
    rBl0 = *(const uint4*)(pBl + o);
    rBl1 = *(const uint4*)(pBl + o + 8);
  };
  auto st = [&]() {
    *(uint4*)&ldsA[0][rowA][chA] = rAh;
    *(uint4*)&ldsA[1][rowA][chA] = rAl;
    *(uint4*)&ldsB[0][rowB][chB] = rBh0;
    *(uint4*)&ldsB[0][rowB][chB + 8] = rBh1;
    *(uint4*)&ldsB[1][rowB][chB] = rBl0;
    *(uint4*)&ldsB[1][rowB][chB + 8] = rBl1;
  };
  int w = tid >> 6, lane = tid & 63;
  int q = lane >> 4, l16 = lane & 15;
  int mh = w >> 1, nh = w & 1;
  f32x4 zf = {0.f, 0.f, 0.f, 0.f};
  f32x4 acc[2][4];
#pragma unroll
  for (int s = 0; s < 2; ++s)
#pragma unroll
    for (int t = 0; t < 4; ++t) acc[s][t] = zf;
  ld(0); st(); __syncthreads();
  for (int c = 0; c < 10; ++c) {
    if (c < 9) ld(c + 1);
    bf16x8 ah0 = *(const bf16x8*)&ldsA[0][mh * 32 + l16][q * 8];
    bf16x8 ah1 = *(const bf16x8*)&ldsA[0][mh * 32 + 16 + l16][q * 8];
    bf16x8 al0 = *(const bf16x8*)&ldsA[1][mh * 32 + l16][q * 8];
    bf16x8 al1 = *(const bf16x8*)&ldsA[1][mh * 32 + 16 + l16][q * 8];
#pragma unroll
    for (int t = 0; t < 4; ++t) {
      int brow = nh * 64 + t * 16 + l16;
      bf16x8 bh = *(const bf16x8*)&ldsB[0][brow][q * 8];
      bf16x8 bl = *(const bf16x8*)&ldsB[1][brow][q * 8];
      acc[0][t] = __builtin_amdgcn_mfma_f32_16x16x32_bf16(ah0, bh, acc[0][t], 0, 0, 0);
      acc[0][t] = __builtin_amdgcn_mfma_f32_16x16x32_bf16(ah0, bl, acc[0][t], 0, 0, 0);
      acc[0][t] = __builtin_amdgcn_mfma_f32_16x16x32_bf16(al0, bh, acc[0][t], 0, 0, 0);
      acc[1][t] = __builtin_amdgcn_mfma_f32_16x16x32_bf16(ah1, bh, acc[1][t], 0, 0, 0);
      acc[1][t] = __builtin_amdgcn_mfma_f32_16x16x32_bf16(ah1, bl, acc[1][t], 0, 0, 0);
      acc[1][t] = __builtin_amdgcn_mfma_f32_16x16x32_bf16(al1, bh, acc[1][t], 0, 0, 0);
    }
    __syncthreads();
    if (c < 9) st();
    __syncthreads();
  }
#pragma unroll
  for (int t = 0; t < 4; ++t) {
    int n = n0 + nh * 64 + t * 16 + l16;
    bool nin = n < N;
    float bz = (bias && nin) ? bias[n] : 0.f;
#pragma unroll
    for (int s = 0; s < 2; ++s) {
#pragma unroll
      for (int r = 0; r < 4; ++r) {
        int m = m0 + mh * 32 + s * 16 + q * 4 + r;
        if (m >= M) continue;
        float v = acc[s][t][r] + bz;
        if (relu) v = v > 0.f ? v : 0.f;
        if (Cf && nin) Cf[(size_t)m * N + n] = v;
        if (Chi && n < KPAD) {
          ushort h = 0, l = 0;
          if (nin) { h = f2bf(v); l = f2bf(v - bf2f(h)); }
          Chi[(size_t)m * KPAD + n] = h;
          Clo[(size_t)m * KPAD + n] = l;
        }
      }
    }
  }
}

// --- K4: normalize henc (hi/lo) -> hn hi/lo [NS][KPAD] (unit rows) ---------
__global__ __launch_bounds__(256) void k_norm_split(
    const ushort* __restrict__ hehi, const ushort* __restrict__ helo,
    ushort* __restrict__ hnhi, ushort* __restrict__ hnlo) {
  int s = blockIdx.x * 4 + (threadIdx.x >> 6);
  int lane = threadIdx.x & 63;
  if (s >= NS) return;
  const ushort* ph = hehi + (size_t)s * KPAD;
  const ushort* pl = helo + (size_t)s * KPAD;
  float x[5];
  float ss = 0.f;
#pragma unroll
  for (int q = 0; q < 5; ++q) {
    int d = lane + q * 64;
    x[q] = bf2f(ph[d]) + bf2f(pl[d]);
    ss += x[q] * x[q];
  }
#pragma unroll
  for (int off = 32; off > 0; off >>= 1) ss += __shfl_down(ss, off, 64);
  ss = __shfl(ss, 0, 64);
  float inv = 1.f / (sqrtf(ss) + 1e-8f);
  ushort* qh = hnhi + (size_t)s * KPAD;
  ushort* ql = hnlo + (size_t)s * KPAD;
#pragma unroll
  for (int q = 0; q < 5; ++q) {
    int d = lane + q * 64;
    float v = x[q] * inv;
    ushort h = f2bf(v);
    qh[d] = h;
    ql[d] = f2bf(v - bf2f(h));
  }
}

// --- K5: cost as gathered MFMA GEMM (hn·hn^T) + fused exp, wave = 32x32 ----
__global__ __launch_bounds__(256) void k_cost_mfma(
    const ushort* __restrict__ hnhi, const ushort* __restrict__ hnlo,
    const int* __restrict__ ridx, const int* __restrict__ cidx,
    const int* __restrict__ rlen, const int* __restrict__ clen,
    float* __restrict__ Kmat) {
  int b = blockIdx.z;
  int r0 = blockIdx.x * 64, c0 = blockIdx.y * 64;
  int rl = rlen[b], cl = clen[b];
  float* Kg = Kmat + (size_t)b * NMAX * MMAX;
  int tid = threadIdx.x;
  if (r0 >= rl || c0 >= cl) {
    for (int l = tid; l < 64 * 16; l += 256) {
      int i = l >> 4, j = (l & 15) << 2;
      *(float4*)&Kg[(size_t)(r0 + i) * MMAX + c0 + j] =
          make_float4(0.f, 0.f, 0.f, 0.f);
    }
    return;
  }
  __shared__ int rix[64], cix[64];
  __shared__ __align__(16) ushort lds[4][64][40];  // Rhi,Rlo,Chi,Clo
  if (tid < 64) rix[tid] = ridx[b * NMAX + r0 + tid];
  else if (tid < 128) cix[tid - 64] = cidx[b * MMAX + c0 + tid - 64];
  __syncthreads();
  int row = tid >> 2, ch = tid & 3;
  const ushort* pRh = hnhi + (size_t)rix[row] * KPAD + ch * 8;
  const ushort* pRl = hnlo + (size_t)rix[row] * KPAD + ch * 8;
  const ushort* pCh = hnhi + (size_t)cix[row] * KPAD + ch * 8;
  const ushort* pCl = hnlo + (size_t)cix[row] * KPAD + ch * 8;
  uint4 rRh, rRl, rCh, rCl;
  auto ld = [&](int c) {
    int o = c * 32;
    rRh = *(const uint4*)(pRh + o);
    rRl = *(const uint4*)(pRl + o);
    rCh = *(const uint4*)(pCh + o);
    rCl = *(const uint4*)(pCl + o);
  };
  auto st = [&]() {
    *(uint4*)&lds[0][row][ch * 8] = rRh;
    *(uint4*)&lds[1][row][ch * 8] = rRl;
    *(uint4*)&lds[2][row][ch * 8] = rCh;
    *(uint4*)&lds[3][row][ch * 8] = rCl;
  };
  int w = tid >> 6, lane = tid & 63;
  int q = lane >> 4, l16 = lane & 15;
  int mh = w >> 1, nh = w & 1;
  f32x4 zf = {0.f, 0.f, 0.f, 0.f};
  f32x4 acc[2][2];
#pragma unroll
  for (int s = 0; s < 2; ++s)
#pragma unroll
    for (int t = 0; t < 2; ++t) acc[s][t] = zf;
  ld(0); st(); __syncthreads();
  for (int c = 0; c < 10; ++c) {
    if (c < 9) ld(c + 1);
    bf16x8 ah0 = *(const bf16x8*)&lds[0][mh * 32 + l16][q * 8];
    bf16x8 ah1 = *(const bf16x8*)&lds[0][mh * 32 + 16 + l16][q * 8];
    bf16x8 al0 = *(const bf16x8*)&lds[1][mh * 32 + l16][q * 8];
    bf16x8 al1 = *(const bf16x8*)&lds[1][mh * 32 + 16 + l16][q * 8];
#pragma unroll
    for (int t = 0; t < 2; ++t) {
      int brow = nh * 32 + t * 16 + l16;
      bf16x8 bh = *(const bf16x8*)&lds[2][brow][q * 8];
      bf16x8 bl = *(const bf16x8*)&lds[3][brow][q * 8];
      acc[0][t] = __builtin_amdgcn_mfma_f32_16x16x32_bf16(ah0, bh, acc[0][t], 0, 0, 0);
      acc[0][t] = __builtin_amdgcn_mfma_f32_16x16x32_bf16(ah0, bl, acc[0][t], 0, 0, 0);
      acc[0][t] = __builtin_amdgcn_mfma_f32_16x16x32_bf16(al0, bh, acc[0][t], 0, 0, 0);
      acc[1][t] = __builtin_amdgcn_mfma_f32_16x16x32_bf16(ah1, bh, acc[1][t], 0, 0, 0);
      acc[1][t] = __builtin_amdgcn_mfma_f32_16x16x32_bf16(ah1, bl, acc[1][t], 0, 0, 0);
      acc[1][t] = __builtin_amdgcn_mfma_f32_16x16x32_bf16(al1, bh, acc[1][t], 0, 0, 0);
    }
    __syncthreads();
    if (c < 9) st();
    __syncthreads();
  }
#pragma unroll
  for (int t = 0; t < 2; ++t) {
    int n = c0 + nh * 32 + t * 16 + l16;
#pragma unroll
    for (int s = 0; s < 2; ++s) {
#pragma unroll
      for (int r = 0; r < 4; ++r) {
        int m = r0 + mh * 32 + s * 16 + q * 4 + r;
        float kv = (m < rl && n < cl) ? expf((acc[s][t][r] - 1.f) / EPSR) : 0.f;
        Kg[(size_t)m * MMAX + n] = kv;
      }
    }
  }
}

// --------- K6: Sinkhorn, K held in VGPRs (kr row / kt col slices) ----------
__global__ __launch_bounds__(512) void k_sinkhorn(
    float* __restrict__ Kmat, const int* __restrict__ rlen,
    const int* __restrict__ clen) {
  __shared__ __align__(16) float vq[4][36];
  __shared__ __align__(16) float uq[4][36];
  int b = blockIdx.x;
  int tid = threadIdx.x;
  int n = tid >> 2, q = tid & 3;
  int rl = rlen[b], cl = clen[b];
  float* Kg = Kmat + (size_t)b * NMAX * MMAX;
  float kr[32], kt[32];
  const float4* Kg4 = (const float4*)(Kg + (size_t)n * MMAX + 32 * q);
#pragma unroll
  for (int t = 0; t < 8; ++t) *(float4*)&kr[4 * t] = Kg4[t];
#pragma unroll
  for (int j = 0; j < 32; ++j) kt[j] = Kg[(size_t)(32 * q + j) * MMAX + n];
  if (tid < 128) vq[tid >> 5][tid & 31] = (tid < cl) ? 1.f : 0.f;
  float av = (n < rl) ? 1.f / (float)rl : 0.f;
  float bv = (n < cl) ? 1.f / (float)cl : 0.f;
  float un = 0.f;
  __syncthreads();
  for (int it = 0; it < SITERS; ++it) {
    float s = 0.f;
#pragma unroll
    for (int t = 0; t < 8; ++t) {
      float4 vv = *(const float4*)&vq[q][4 * t];
      s += kr[4 * t + 0] * vv.x + kr[4 * t + 1] * vv.y +
           kr[4 * t + 2] * vv.z + kr[4 * t + 3] * vv.w;
    }
    s += __shfl_xor(s, 1, 64);
    s += __shfl_xor(s, 2, 64);
    un = (n < rl) ? av / s : 0.f;
    if (q == 0) uq[n >> 5][n & 31] = un;
    __syncthreads();
    float s2 = 0.f;
#pragma unroll
    for (int t = 0; t < 8; ++t) {
      float4 uu = *(const float4*)&uq[q][4 * t];
      s2 += kt[4 * t + 0] * uu.x + kt[4 * t + 1] * uu.y +
            kt[4 * t + 2] * uu.z + kt[4 * t + 3] * uu.w;
    }
    s2 += __shfl_xor(s2, 1, 64);
    s2 += __shfl_xor(s2, 2, 64);
    float vm = (n < cl) ? bv / s2 : 0.f;
    if (q == 0) vq[n >> 5][n & 31] = vm;
    __syncthreads();
  }
  float4* Pg4 = (float4*)(Kg + (size_t)n * MMAX + 32 * q);
#pragma unroll
  for (int t = 0; t < 8; ++t) {
    float4 vv = *(const float4*)&vq[q][4 * t];
    float4 p;
    p.x = un * kr[4 * t + 0] * vv.x;
    p.y = un * kr[4 * t + 1] * vv.y;
    p.z = un * kr[4 * t + 2] * vv.z;
    p.w = un * kr[4 * t + 3] * vv.w;
    Pg4[t] = p;
  }
}

// ---- K7: attend + compare + masked sum; BOTH sides in one dispatch --------
// blockIdx.z = side (0: rows-main, 1: cols-main). Same math as the R9/R11
// per-side kernels — merged so both sides' blocks co-schedule (2560 blocks
// vs 2x1280 serialized), filling latency bubbles.
__global__ __launch_bounds__(256) void k_att_cmp_both(
    const float* __restrict__ P, const float* __restrict__ HcB,
    const int* __restrict__ row_idx, const int* __restrict__ col_idx,
    const int* __restrict__ row_len, const int* __restrict__ col_len,
    const float* __restrict__ bc, float* __restrict__ cr,
    float* __restrict__ cc) {
  int b = blockIdx.y;
  int side = blockIdx.z;
  int c0 = blockIdx.x * 64;
  const int* idx_main = side == 0 ? row_idx : col_idx;
  const int* idx_other = side == 0 ? col_idx : row_idx;
  int lm = side == 0 ? row_len[b] : col_len[b];
  int lo = side == 0 ? col_len[b] : row_len[b];
  float* outacc = side == 0 ? cr : cc;
  __shared__ __align__(16) float smem[2][2][16][68];  // [buf][P|G]
  __shared__ int iox[NMAX];
  __shared__ int imx[NMAX];
  int tid = threadIdx.x, tx = tid & 15, ty = tid >> 4;
  int jj = tid & 63, kq = tid >> 6;
  if (tid < 128) iox[tid] = idx_other[b * NMAX + tid];
  else imx[tid - 128] = idx_main[b * NMAX + tid - 128];
  __syncthreads();
  const float* Pb = P + (size_t)b * NMAX * MMAX;
  bool cok = (c0 + jj) < HDIM;
  int nkc = (lo + 15) >> 4;
  int nmt = (lm + 63) >> 6;
  float pR[4], gR[4];
  auto loadPG = [&](int mt, int kc) {
    int m0 = mt * 64, k0 = kc * 16;
    if (side == 0) {
#pragma unroll
      for (int p = 0; p < 4; ++p)
        pR[p] = Pb[(size_t)(m0 + ty + p * 16) * MMAX + k0 + tx];
    } else {
#pragma unroll
      for (int p = 0; p < 4; ++p)
        pR[p] = Pb[(size_t)(k0 + kq + p * 4) * MMAX + m0 + jj];
    }
#pragma unroll
    for (int p = 0; p < 4; ++p) {
      int row = iox[k0 + kq + p * 4];
      gR[p] = cok ? HcB[(size_t)row * 600 + 300 + c0 + jj] : 0.f;
    }
  };
  auto storePG = [&](int buf) {
    if (side == 0) {
#pragma unroll
      for (int p = 0; p < 4; ++p) smem[buf][0][tx][ty + p * 16] = pR[p];
    } else {
#pragma unroll
      for (int p = 0; p < 4; ++p) smem[buf][0][kq + p * 4][jj] = pR[p];
    }
#pragma unroll
    for (int p = 0; p < 4; ++p) smem[buf][1][kq + p * 4][jj] = gR[p];
  };
  float colsum[4] = {0.f, 0.f, 0.f, 0.f};
  loadPG(0, 0);
  storePG(0);
  __syncthreads();
  int cur = 0;
  for (int mt = 0; mt < nmt; ++mt) {
    float acc[4][4] = {};
    for (int kc = 0; kc < nkc; ++kc) {
      bool last = (mt == nmt - 1) && (kc == nkc - 1);
      if (!last) {
        int nm = (kc + 1 < nkc) ? mt : mt + 1;
        int nk = (kc + 1 < nkc) ? kc + 1 : 0;
        loadPG(nm, nk);
      }
#pragma unroll
      for (int kk = 0; kk < 16; ++kk) {
        float4 av = *(const float4*)&smem[cur][0][kk][ty * 4];
        float4 gv = *(const float4*)&smem[cur][1][kk][tx * 4];
        float a[4] = {av.x, av.y, av.z, av.w};
        float g[4] = {gv.x, gv.y, gv.z, gv.w};
#pragma unroll
        for (int i = 0; i < 4; ++i)
#pragma unroll
          for (int j = 0; j < 4; ++j) acc[i][j] += a[i] * g[j];
      }
      if (!last) storePG(cur ^ 1);
      __syncthreads();
      cur ^= 1;
    }
#pragma unroll
    for (int i = 0; i < 4; ++i) {
      int mi = mt * 64 + ty * 4 + i;
      if (mi >= lm) continue;
      int hrow = imx[mi];
#pragma unroll
      for (int j = 0; j < 4; ++j) {
        int col = c0 + tx * 4 + j;
        if (col >= HDIM) continue;
        float y = acc[i][j] + HcB[(size_t)hrow * 600 + col] + bc[col];
        colsum[j] += y > 0.f ? y : 0.f;
      }
    }
  }
  __syncthreads();
  float(*red)[68] = (float(*)[68]) & smem[0][0][0][0];
#pragma unroll
  for (int j = 0; j < 4; ++j) red[ty][tx * 4 + j] = colsum[j];
  __syncthreads();
  if (tid < 64) {
    float s = 0.f;
#pragma unroll
    for (int r = 0; r < 16; ++r) s += red[r][tid];
    int col = c0 + tid;
    if (col < HDIM) outacc[(size_t)b * HDIM + col] = s;
  }
}

// ---------------- K8: classifier head -> out [B,2] -------------------------
__global__ __launch_bounds__(320) void k_cls(
    const float* __restrict__ cr, const float* __restrict__ cc,
    const float* __restrict__ Wcls, const float* __restrict__ bcls,
    const float* __restrict__ Wout, const float* __restrict__ bout,
    float* __restrict__ out) {
  __shared__ __align__(16) float cz[2 * HDIM];
  __shared__ float zz[HDIM];
  int b = blockIdx.x, tid = threadIdx.x;
  if (tid < HDIM) {
    cz[tid] = cr[(size_t)b * HDIM + tid];
    cz[HDIM + tid] = cc[(size_t)b * HDIM + tid];
  }
  __syncthreads();
  if (tid < HDIM) {
    float acc = bcls[tid];
    for (int k4 = 0; k4 < 2 * HDIM; k4 += 4) {
      float4 c = *(const float4*)&cz[k4];
      acc += c.x * Wcls[(size_t)(k4 + 0) * HDIM + tid] +
             c.y * Wcls[(size_t)(k4 + 1) * HDIM + tid] +
             c.z * Wcls[(size_t)(k4 + 2) * HDIM + tid] +
             c.w * Wcls[(size_t)(k4 + 3) * HDIM + tid];
    }
    zz[tid] = acc > 0.f ? acc : 0.f;
  }
  __syncthreads();
  int o = tid >> 6, lane = tid & 63;
  if (o < 2) {
    float p = 0.f;
    for (int j = lane; j < HDIM; j += 64) p += zz[j] * Wout[(size_t)j * 2 + o];
#pragma unroll
    for (int off = 32; off > 0; off >>= 1) p += __shfl_down(p, off, 64);
    if (lane == 0) out[b * 2 + o] = p + bout[o];
  }
}

extern "C" void kernel_launch(void* const* d_in, const int* in_sizes, int n_in,
                              void* d_out, int out_size, void* d_ws, size_t ws_size,
                              hipStream_t stream) {
  (void)in_sizes; (void)n_in; (void)out_size; (void)ws_size;
  const int* data = (const int*)d_in[0];
  const int* row_idx = (const int*)d_in[1];
  const int* col_idx = (const int*)d_in[2];
  const int* row_len = (const int*)d_in[3];
  const int* col_len = (const int*)d_in[4];
  const float* emb = (const float*)d_in[5];
  const float* W1 = (const float*)d_in[6];
  const float* b1 = (const float*)d_in[7];
  const float* W2 = (const float*)d_in[8];
  const float* b2 = (const float*)d_in[9];
  const float* Wc = (const float*)d_in[10];
  const float* bc = (const float*)d_in[11];
  const float* Wcls = (const float*)d_in[12];
  const float* bcls = (const float*)d_in[13];
  const float* Wout = (const float*)d_in[14];
  const float* bout = (const float*)d_in[15];
  float* out = (float*)d_out;

  char* wp = (char*)d_ws;
  auto carve = [&](size_t bytes) {
    char* p = wp; wp += (bytes + 255) & ~(size_t)255; return p;
  };
  ushort* enchi = (ushort*)carve((size_t)NS * KPAD * 2);
  ushort* enclo = (ushort*)carve((size_t)NS * KPAD * 2);
  ushort* h1hi = (ushort*)carve((size_t)NS * KPAD * 2);
  ushort* h1lo = (ushort*)carve((size_t)NS * KPAD * 2);
  ushort* hehi = (ushort*)carve((size_t)NS * KPAD * 2);
  ushort* helo = (ushort*)carve((size_t)NS * KPAD * 2);
  ushort* hnhi = (ushort*)carve((size_t)NS * KPAD * 2);
  ushort* hnlo = (ushort*)carve((size_t)NS * KPAD * 2);
  ushort* W1hi = (ushort*)carve((size_t)NPADW * KPAD * 2);
  ushort* W1lo = (ushort*)carve((size_t)NPADW * KPAD * 2);
  ushort* W2hi = (ushort*)carve((size_t)NPADW * KPAD * 2);
  ushort* W2lo = (ushort*)carve((size_t)NPADW * KPAD * 2);
  ushort* Wchi = (ushort*)carve((size_t)640 * KPAD * 2);
  ushort* Wclo = (ushort*)carve((size_t)640 * KPAD * 2);
  float* HcB = (float*)carve((size_t)NS * 600 * 4);
  float* Km = (float*)carve((size_t)BB * NMAX * MMAX * 4);
  float* cr = (float*)carve((size_t)BB * HDIM * 4);
  float* cc = (float*)carve((size_t)BB * HDIM * 4);

  int gM = (NS + 63) / 64;  // 157
  int cvtTotal = 2 * NPADW * KPAD + 640 * KPAD;

  k_embed<<<NS, 256, 0, stream>>>(data, emb, enchi, enclo);
  k_cvt_all<<<(cvtTotal + 255) / 256, 256, 0, stream>>>(
      W1, W2, Wc, W1hi, W1lo, W2hi, W2lo, Wchi, Wclo);
  k_gemm_mfma<<<dim3(gM, 3), 256, 0, stream>>>(
      enchi, enclo, W1hi, W1lo, b1, NS, HDIM, 1, nullptr, h1hi, h1lo);
  k_gemm_mfma<<<dim3(gM, 3), 256, 0, stream>>>(
      h1hi, h1lo, W2hi, W2lo, b2, NS, HDIM, 1, nullptr, hehi, helo);
  k_norm_split<<<(NS + 3) / 4, 256, 0, stream>>>(hehi, helo, hnhi, hnlo);
  k_gemm_mfma<<<dim3(gM, 5), 256, 0, stream>>>(
      hehi, helo, Wchi, Wclo, nullptr, NS, 2 * HDIM, 0, HcB, nullptr, nullptr);
  k_cost_mfma<<<dim3(2, 2, BB), 256, 0, stream>>>(hnhi, hnlo, row_idx, col_idx,
                                                  row_len, col_len, Km);
  k_sinkhorn<<<BB, 512, 0, stream>>>(Km, row_len, col_len);
  k_att_cmp_both<<<dim3(5, BB, 2), 256, 0, stream>>>(
      Km, HcB, row_idx, col_idx, row_len, col_len, bc, cr, cc);
  k_cls<<<BB, 320, 0, stream>>>(cr, cc, Wcls, bcls, Wout, bout, out);
}